// Round 5
// baseline (127.728 us; speedup 1.0000x reference)
//
#include <hip/hip_runtime.h>
#include <hip/hip_bf16.h>
#include <cstdint>
#include <cstddef>

// Problem constants
#define B_ 8
#define S_ 2048
#define D_ 1024
#define RFAC 32.0f
#define ALPHA 0.2f
#define BETA 0.1f
#define GAMMA 0.1f
// EMA truncation window: 0.8^32 ~ 8e-4 ~ bf16 noise floor (threshold 0.108)
#define KW 32
#define TB 64
#define PF_ 8   // ema prefetch pipeline depth (static ring, fully unrolled)

typedef float f32x4_t __attribute__((ext_vector_type(4)));
typedef short bf16x8_t __attribute__((ext_vector_type(8)));

__device__ __forceinline__ unsigned short f2bf(float f) {
    unsigned u = __float_as_uint(f);
    u = (u + 0x7fffu + ((u >> 16) & 1u)) >> 16;
    return (unsigned short)u;
}
__device__ __forceinline__ float bf2f(unsigned short h) {
    return __uint_as_float(((unsigned)h) << 16);
}

// ---------------------------------------------------------------------------
// Kernel 1: streaming bf16 cast + row-norm scalars. One wave per row.
// bf16 stores have NO dependency on the norm (scale deferred to ema via
// rnq/rnk), so this is a pure stream: no row residency, no spill/reload.
__global__ __launch_bounds__(256) void normalize_k(const float* __restrict__ q,
                                                   const float* __restrict__ k,
                                                   unsigned short* __restrict__ qh,
                                                   unsigned short* __restrict__ kh,
                                                   float* __restrict__ rnq,
                                                   float* __restrict__ rnk) {
    int row  = blockIdx.x * 4 + (threadIdx.x >> 6);
    int lane = threadIdx.x & 63;
    const float4* qr = (const float4*)(q + (size_t)row * D_);
    const float4* kr = (const float4*)(k + (size_t)row * D_);
    ushort4* qo = (ushort4*)(qh + (size_t)row * D_);
    ushort4* ko = (ushort4*)(kh + (size_t)row * D_);
    float sq = 0.f, sk = 0.f;
#pragma unroll
    for (int j = 0; j < 4; ++j) {
        float4 a = qr[lane + 64 * j];
        float4 b = kr[lane + 64 * j];
        sq += a.x * a.x + a.y * a.y + a.z * a.z + a.w * a.w;
        sk += b.x * b.x + b.y * b.y + b.z * b.z + b.w * b.w;
        ushort4 oq, ok;
        oq.x = f2bf(a.x); oq.y = f2bf(a.y); oq.z = f2bf(a.z); oq.w = f2bf(a.w);
        ok.x = f2bf(b.x); ok.y = f2bf(b.y); ok.z = f2bf(b.z); ok.w = f2bf(b.w);
        qo[lane + 64 * j] = oq;
        ko[lane + 64 * j] = ok;
    }
#pragma unroll
    for (int off = 32; off > 0; off >>= 1) {
        sq += __shfl_xor(sq, off, 64);
        sk += __shfl_xor(sk, off, 64);
    }
    if (lane == 0) {
        rnq[row] = ALPHA / (sqrtf(sq) + 1e-6f);
        rnk[row] = ALPHA / (sqrtf(sk) + 1e-6f);
    }
}

// ---------------------------------------------------------------------------
// Kernel 2: W -> bf16 convert.
__global__ __launch_bounds__(256) void wconv_k(const float* __restrict__ W,
                                               unsigned short* __restrict__ Wb) {
    int i = blockIdx.x * 256 + threadIdx.x;
    float4 w = ((const float4*)W)[i];
    ushort4 o;
    o.x = f2bf(w.x); o.y = f2bf(w.y); o.z = f2bf(w.z); o.w = f2bf(w.w);
    ((ushort4*)Wb)[i] = o;
}

// ---------------------------------------------------------------------------
// Kernel 3: fused windowed EMA + coef, software-pipelined (depth PF_=8).
// Reads unscaled bf16 q,k + per-row scalars rnq,rnk (ring-prefetched).
__global__ __launch_bounds__(256) void ema_coef_k(const unsigned short* __restrict__ qh,
                                                  const unsigned short* __restrict__ kh,
                                                  const float* __restrict__ rnq,
                                                  const float* __restrict__ rnk,
                                                  const float* __restrict__ vv,
                                                  unsigned short* __restrict__ Ub,
                                                  float* __restrict__ coef) {
    __shared__ float sm[TB * 8];   // [t][wave*2 + {uu,sd}]
    const int chunks = S_ / TB;
    int b  = blockIdx.x / chunks;
    int t0 = (blockIdx.x % chunks) * TB;
    int ts = t0 - KW; if (ts < 0) ts = 0;
    int tid = threadIdx.x;
    int lane = tid & 63, wave = tid >> 6;
    size_t bbase = (size_t)b * S_ * D_ + tid * 4;
    const unsigned short* qp = qh + bbase;
    const unsigned short* kp = kh + bbase;
    const float* vp = vv + bbase;
    unsigned short* up = Ub + bbase;
    const float* rq = rnq + b * S_;
    const float* rk = rnk + b * S_;

    ushort4 pq[PF_], pk[PF_];
    float4 pv[PF_];
    float paq[PF_], pak[PF_];
#pragma unroll
    for (int j = 0; j < PF_; ++j) {
        size_t o = (size_t)(ts + j) * D_;
        pq[j] = *(const ushort4*)(qp + o);
        pk[j] = *(const ushort4*)(kp + o);
        paq[j] = rq[ts + j];
        pak[j] = rk[ts + j];
        if (ts + j >= t0) pv[j] = *(const float4*)(vp + o);
    }
    float u0 = 0.f, u1 = 0.f, u2 = 0.f, u3 = 0.f;
    float v0 = 0.f, v1 = 0.f, v2 = 0.f, v3 = 0.f;
    const float om = 1.f - ALPHA;
    const int NI = t0 + TB - ts;       // 64 (chunk 0) or 96; both % 8 == 0
    const int tend = t0 + TB;
    for (int g = 0; g < NI; g += PF_) {
#pragma unroll
        for (int j = 0; j < PF_; ++j) {
            int t = ts + g + j;
            float aq = paq[j], ak = pak[j];
            u0 = om * u0 + aq * bf2f(pq[j].x); u1 = om * u1 + aq * bf2f(pq[j].y);
            u2 = om * u2 + aq * bf2f(pq[j].z); u3 = om * u3 + aq * bf2f(pq[j].w);
            v0 = om * v0 + ak * bf2f(pk[j].x); v1 = om * v1 + ak * bf2f(pk[j].y);
            v2 = om * v2 + ak * bf2f(pk[j].z); v3 = om * v3 + ak * bf2f(pk[j].w);
            if (t >= t0) {               // wave-uniform branch
                float uu = u0 * u0 + u1 * u1 + u2 * u2 + u3 * u3;
                float sd = v0 * pv[j].x + v1 * pv[j].y + v2 * pv[j].z + v3 * pv[j].w;
#pragma unroll
                for (int off = 32; off > 0; off >>= 1) {
                    uu += __shfl_xor(uu, off, 64);
                    sd += __shfl_xor(sd, off, 64);
                }
                if (lane == 0) {
                    sm[(t - t0) * 8 + wave * 2 + 0] = uu;
                    sm[(t - t0) * 8 + wave * 2 + 1] = sd;
                }
                ushort4 us;
                us.x = f2bf(u0); us.y = f2bf(u1); us.z = f2bf(u2); us.w = f2bf(u3);
                *(ushort4*)(up + (size_t)t * D_) = us;
            }
            // prefetch t+PF_ into slot j (clamped; duplicate loads harmless)
            int tf = t + PF_;
            int tc = tf < tend ? tf : tend - 1;
            size_t o2 = (size_t)tc * D_;
            pq[j] = *(const ushort4*)(qp + o2);
            pk[j] = *(const ushort4*)(kp + o2);
            paq[j] = rq[tc];
            pak[j] = rk[tc];
            if (tf >= t0) pv[j] = *(const float4*)(vp + o2);
        }
    }
    __syncthreads();
    if (tid < TB) {
        float uu = sm[tid * 8 + 0] + sm[tid * 8 + 2] + sm[tid * 8 + 4] + sm[tid * 8 + 6];
        float sd = sm[tid * 8 + 1] + sm[tid * 8 + 3] + sm[tid * 8 + 5] + sm[tid * 8 + 7];
        float nrm = RFAC * fabsf(sd) * sqrtf(uu);
        float n = fmaxf(nrm, 1e-6f);
        coef[b * S_ + t0 + tid] = GAMMA * RFAC * sd / (1.f + BETA * (n - 1.f));
    }
}

// ---------------------------------------------------------------------------
// Kernel 4: out[m,n] = x[m,n] + coef[m] * sum_d U[m,d] * W[n,d]
// 256x256 tile, BK=64, 8 waves (2Mx4N), double-buffered LDS (128 KB),
// 4 quadrant-phases per K-tile; vmcnt drained ONCE per K-tile.
#define BM 256
#define BN 256
#define BK 64
#define NT (D_ / BK)   // 16 K-tiles

__global__ __launch_bounds__(512, 2) void gemm_k(const unsigned short* __restrict__ A,   // M x K bf16
                                                 const unsigned short* __restrict__ Bw,  // N x K bf16
                                                 const float* __restrict__ coef,
                                                 const float* __restrict__ x,
                                                 float* __restrict__ out) {
    const int N = D_, K = D_;
    __shared__ unsigned short lds[2 * 2 * BM * BK];   // [buf][A|B], 128 KiB
    int bid = blockIdx.x;
    int swz = (bid & 7) * 32 + (bid >> 3);   // XCD-aware, 256 % 8 == 0 (bijective)
    int tm = swz >> 2, tn = swz & 3;         // N/BN = 4
    int m0 = tm * BM, n0 = tn * BN;
    int tid = threadIdx.x;
    int lane = tid & 63;
    int wid = tid >> 6;
    int wm = wid >> 2, wn = wid & 3;         // 2x4 wave grid; wave tile 128x64
    int lr = lane & 15, lg = lane >> 4;

    f32x4_t acc[8][4];
#pragma unroll
    for (int i = 0; i < 8; ++i)
#pragma unroll
        for (int j = 0; j < 4; ++j)
            acc[i][j] = (f32x4_t){0.f, 0.f, 0.f, 0.f};

#define STAGE_HALF(buf, kt, h)                                                        \
    {                                                                                 \
        int isB = (h) >> 1;                                                           \
        const unsigned short* Gp =                                                    \
            (isB ? Bw + (size_t)n0 * K : A + (size_t)m0 * K) + (size_t)(kt) * BK;     \
        unsigned short* Lp = lds + (buf) * 32768 + isB * 16384;                       \
        _Pragma("unroll")                                                             \
        for (int i = 0; i < 2; ++i) {                                                 \
            int c = i * 512 + tid;            /* 0..1023 16B chunks of the half */    \
            int row = ((h) & 1) * 128 + (c >> 3);                                     \
            int cl = c & 7;                                                           \
            int gc = cl ^ (row & 7);          /* pre-swizzled global chunk */         \
            __builtin_amdgcn_global_load_lds(                                         \
                (const __attribute__((address_space(1))) void*)(Gp + (size_t)row * K + gc * 8), \
                (__attribute__((address_space(3))) void*)((char*)Lp + (((((h)&1)*128 + (c>>3)) * 8 + cl) * 16)), \
                16, 0, 0);                                                            \
        }                                                                             \
    }

    STAGE_HALF(0, 0, 0); STAGE_HALF(0, 0, 1); STAGE_HALF(0, 0, 2); STAGE_HALF(0, 0, 3);
    __syncthreads();

    for (int t = 0; t < NT; ++t) {
        const unsigned short* La = lds + (t & 1) * 32768;
        const unsigned short* Lb = La + 16384;
        int nb = (t + 1) & 1;
        bool more = (t + 1 < NT);
        bf16x8_t bfrag[4][2];
#pragma unroll
        for (int p = 0; p < 4; ++p) {
            if (p == 0) {
#pragma unroll
                for (int ni = 0; ni < 4; ++ni)
#pragma unroll
                    for (int kk = 0; kk < 2; ++kk) {
                        int row = wn * 64 + ni * 16 + lr;
                        int ch = (kk * 4 + lg) ^ (row & 7);
                        bfrag[ni][kk] = *(const bf16x8_t*)(Lb + (row * 8 + ch) * 8);
                    }
            }
            bf16x8_t afrag[2][2];
#pragma unroll
            for (int qq = 0; qq < 2; ++qq)
#pragma unroll
                for (int kk = 0; kk < 2; ++kk) {
                    int row = wm * 128 + p * 32 + qq * 16 + lr;
                    int ch = (kk * 4 + lg) ^ (row & 7);
                    afrag[qq][kk] = *(const bf16x8_t*)(La + (row * 8 + ch) * 8);
                }
            if (more) STAGE_HALF(nb, t + 1, p);          // 2 loads, stay in flight
            __builtin_amdgcn_s_barrier();                // lockstep (no vm drain)
            asm volatile("s_waitcnt lgkmcnt(0)" ::: "memory");
            __builtin_amdgcn_sched_barrier(0);
            __builtin_amdgcn_s_setprio(1);
#pragma unroll
            for (int qq = 0; qq < 2; ++qq)
#pragma unroll
                for (int ni = 0; ni < 4; ++ni)
#pragma unroll
                    for (int kk = 0; kk < 2; ++kk)
                        acc[p * 2 + qq][ni] = __builtin_amdgcn_mfma_f32_16x16x32_bf16(
                            afrag[qq][kk], bfrag[ni][kk], acc[p * 2 + qq][ni], 0, 0, 0);
            __builtin_amdgcn_s_setprio(0);
            if (p < 3) __builtin_amdgcn_s_barrier();     // lockstep (no vm drain)
        }
        __syncthreads();   // ONE vmcnt drain per K-tile
    }
#undef STAGE_HALF

    // Epilogue: C/D layout col = lane&15, row = (lane>>4)*4 + reg
#pragma unroll
    for (int mi = 0; mi < 8; ++mi) {
#pragma unroll
        for (int i = 0; i < 4; ++i) {
            int m = m0 + wm * 128 + mi * 16 + lg * 4 + i;
            float cf = coef[m];
#pragma unroll
            for (int ni = 0; ni < 4; ++ni) {
                int n = n0 + wn * 64 + ni * 16 + lr;
                size_t idx = (size_t)m * N + n;
                out[idx] = x[idx] + cf * acc[mi][ni][i];
            }
        }
    }
}

// ---------------------------------------------------------------------------
extern "C" void kernel_launch(void* const* d_in, const int* in_sizes, int n_in,
                              void* d_out, int out_size, void* d_ws, size_t ws_size,
                              hipStream_t stream) {
    const float* x  = (const float*)d_in[0];
    const float* q  = (const float*)d_in[1];
    const float* k  = (const float*)d_in[2];
    const float* vv = (const float*)d_in[3];
    const float* W  = (const float*)d_in[4];
    float* out = (float*)d_out;

    const size_t M = (size_t)B_ * S_;           // 16384
    char* ws = (char*)d_ws;
    unsigned short* Ub = (unsigned short*)ws;                      // 32MB
    unsigned short* Wb = (unsigned short*)(ws + M * D_ * 2);       // 2MB
    float* coef = (float*)(ws + M * D_ * 2 + (size_t)D_ * D_ * 2);
    float* rnq  = coef + M;
    float* rnk  = rnq + M;
    size_t needed = M * D_ * 2 + (size_t)D_ * D_ * 2 + 3 * M * 4;
    if (ws_size < needed) return;  // fail visibly (output stays poisoned)

    // qh/kh scratch lives in d_out (64MB, dead before gemm writes out)
    unsigned short* qh = (unsigned short*)d_out;
    unsigned short* kh = qh + M * D_;

    normalize_k<<<dim3(M / 4), dim3(256), 0, stream>>>(q, k, qh, kh, rnq, rnk);
    wconv_k<<<dim3((D_ * D_) / 1024), dim3(256), 0, stream>>>(W, Wb);
    ema_coef_k<<<dim3(B_ * (S_ / TB)), dim3(256), 0, stream>>>(qh, kh, rnq, rnk, vv, Ub, coef);
    gemm_k<<<dim3((M / BM) * (D_ / BN)), dim3(512), 0, stream>>>(Ub, Wb, coef, x, out);
}